// Round 12
// baseline (490.587 us; speedup 1.0000x reference)
//
#include <hip/hip_runtime.h>
#include <cfloat>
#include <climits>
#include <cstdint>

#define B_ 16
#define T_ 4096
#define D_ 256
#define K_ 1024
#define BT_ 65536
#define DECAYF 0.99f
#define OMDECAYF 0.01f
#define EPSF 1e-5f
#define TAUGAP 0.125f
#define CHUNK 32
#define GROUP 16
#define RMARGIN 0.01f

typedef float f32x4 __attribute__((ext_vector_type(4)));
typedef _Float16 f16x8 __attribute__((ext_vector_type(8)));

__device__ __forceinline__ void gload16(const void* g, void* l) {
    __builtin_amdgcn_global_load_lds(
        (const __attribute__((address_space(1))) void*)g,
        (__attribute__((address_space(3))) void*)l, 16, 0, 0);
}

// ---------------- prep: z->fp16, E->fp16^T, enorm(fp32+fp64), zero accumulators ----------------
__global__ void k_prep(const float* __restrict__ z, const float* __restrict__ E,
                       _Float16* __restrict__ zf, _Float16* __restrict__ EfT,
                       float* __restrict__ enorm, double* __restrict__ enorm64,
                       int* __restrict__ counts, int* __restrict__ nflag,
                       float* __restrict__ out_closs, float* __restrict__ out_cbl,
                       float* __restrict__ emb_sum) {
    int b = blockIdx.x;
    if (b < 8192) {                       // z: 8 floats/thread -> fp16
        int base = (b * 256 + threadIdx.x) * 8;
        float4 v0 = *(const float4*)(z + base);
        float4 v1 = *(const float4*)(z + base + 4);
        f16x8 h;
        h[0] = (_Float16)v0.x; h[1] = (_Float16)v0.y;
        h[2] = (_Float16)v0.z; h[3] = (_Float16)v0.w;
        h[4] = (_Float16)v1.x; h[5] = (_Float16)v1.y;
        h[6] = (_Float16)v1.z; h[7] = (_Float16)v1.w;
        *(f16x8*)(zf + base) = h;
    } else {                              // E column n: transpose + fp16 + fp64 norm
        __shared__ double rd[256];
        int n = b - 8192, d = threadIdx.x;
        float v = E[(size_t)d * K_ + n];
        EfT[(size_t)n * 256 + d] = (_Float16)v;
        rd[d] = (double)v * (double)v;
        __syncthreads();
        for (int st = 128; st > 0; st >>= 1) {
            if (d < st) rd[d] += rd[d + st];
            __syncthreads();
        }
        if (d == 0) { enorm[n] = (float)rd[0]; enorm64[n] = rd[0]; }
        emb_sum[(size_t)n * 256 + d] = 0.f;
        if (n < 4) counts[n * 256 + d] = 0;
        if (n == 4) {
            if (d < 16) out_closs[d] = 0.f;
            else if (d < 32) out_cbl[d - 16] = 0.f;
            else if (d == 32) *nflag = 0;
        }
    }
}

// ---------------- fp16 MFMA distance GEMM + fused argmin top-2 + histogram ----------------
// R8 loop (proven 110us) with LDS cut to 48KB (merge arrays alias Ab post-loop)
// -> 3 blocks/CU, 24 waves: cross-block overlap hides the barrier drain (m97/m114).
__global__ __launch_bounds__(512, 6) void k_argmin_mfma(
    const _Float16* __restrict__ zf, const _Float16* __restrict__ EfT,
    const float* __restrict__ enorm, int* __restrict__ code,
    int* __restrict__ flags, int* __restrict__ nflag, int* __restrict__ counts) {
    __shared__ _Float16 Ab[2][128 * 32];   // 8KB x2 (epilogue aliases Ab for merge)
    __shared__ _Float16 Bb[2][256 * 32];   // 16KB x2  -> 48KB total

    const int t = threadIdx.x;
    const int row0 = blockIdx.x * 128;
    const int l = t & 63, wid = t >> 6;
    const int wr = wid >> 2, wc = wid & 3;
    const int lr = l & 15, lk = l >> 4;

    const int arow = t >> 2,          ablk = (t & 3) ^ ((arow >> 1) & 3);
    const int brow0 = t >> 2,         bblk0 = (t & 3) ^ ((brow0 >> 1) & 3);
    const int brow1 = (t + 512) >> 2, bblk1 = ((t + 512) & 3) ^ ((brow1 >> 1) & 3);

#define STAGE(it_, buf_) do {                                                       \
        int nc_ = (it_) >> 3; int kb_ = ((it_) & 7) * 32;                            \
        gload16(zf + (size_t)(row0 + arow) * 256 + kb_ + ablk * 8,                   \
                &Ab[buf_][(t & ~63) * 8]);                                           \
        gload16(EfT + (size_t)(nc_ * 256 + brow0) * 256 + kb_ + bblk0 * 8,           \
                &Bb[buf_][(t & ~63) * 8]);                                           \
        gload16(EfT + (size_t)(nc_ * 256 + brow1) * 256 + kb_ + bblk1 * 8,           \
                &Bb[buf_][((t + 512) & ~63) * 8]);                                   \
    } while (0)

    STAGE(0, 0);

    float D1[4][4], D2[4][4];
    int   I1[4][4];
    #pragma unroll
    for (int m = 0; m < 4; ++m)
        #pragma unroll
        for (int r = 0; r < 4; ++r) {
            D1[m][r] = FLT_MAX; D2[m][r] = FLT_MAX; I1[m][r] = 0x7fffffff;
        }

    f32x4 acc[4][4];
    for (int it = 0; it < 32; ++it) {
        if ((it & 7) == 0) {
            #pragma unroll
            for (int m = 0; m < 4; ++m)
                #pragma unroll
                for (int n = 0; n < 4; ++n) acc[m][n] = (f32x4){0.f, 0.f, 0.f, 0.f};
        }
        __syncthreads();                       // buf[it&1] ready
        if (it + 1 < 32) STAGE(it + 1, (it + 1) & 1);
        const _Float16* Abuf = Ab[it & 1];
        const _Float16* Bbuf = Bb[it & 1];
        f16x8 a[4], b[4];
        #pragma unroll
        for (int m = 0; m < 4; ++m) {
            int row = wr * 64 + m * 16 + lr;
            a[m] = *(const f16x8*)&Abuf[row * 32 + ((lk ^ ((row >> 1) & 3)) * 8)];
        }
        #pragma unroll
        for (int n = 0; n < 4; ++n) {
            int nn = wc * 64 + n * 16 + lr;
            b[n] = *(const f16x8*)&Bbuf[nn * 32 + ((lk ^ ((nn >> 1) & 3)) * 8)];
        }
        #pragma unroll
        for (int m = 0; m < 4; ++m)
            #pragma unroll
            for (int n = 0; n < 4; ++n)
                acc[m][n] = __builtin_amdgcn_mfma_f32_16x16x32_f16(
                    a[m], b[n], acc[m][n], 0, 0, 0);

        if ((it & 7) == 7) {                   // fold this nc chunk into running top-2
            int nc = it >> 3;
            float en[4];
            #pragma unroll
            for (int n = 0; n < 4; ++n)
                en[n] = enorm[nc * 256 + wc * 64 + n * 16 + lr];
            #pragma unroll
            for (int m = 0; m < 4; ++m)
                #pragma unroll
                for (int r = 0; r < 4; ++r)
                    #pragma unroll
                    for (int n = 0; n < 4; ++n) {
                        float dist = en[n] - 2.0f * acc[m][n][r];
                        int cg = nc * 256 + wc * 64 + n * 16 + lr;
                        if (dist < D1[m][r]) {
                            D2[m][r] = D1[m][r]; D1[m][r] = dist; I1[m][r] = cg;
                        } else D2[m][r] = fminf(D2[m][r], dist);
                    }
        }
    }
#undef STAGE

    // ---- final merge: 16 lr-lanes -> mg (aliased on Ab) -> 4 wc ----
    __syncthreads();   // all Ab/Bb reads complete; safe to reuse Ab as merge scratch
    float* mg_d1 = (float*)&Ab[0][0];
    int*   mg_i1 = (int*)(mg_d1 + 512);
    float* mg_d2 = (float*)(mg_i1 + 512);

    #pragma unroll
    for (int m = 0; m < 4; ++m)
        #pragma unroll
        for (int r = 0; r < 4; ++r) {
            float d1 = D1[m][r], d2 = D2[m][r];
            int i1 = I1[m][r];
            #pragma unroll
            for (int mask = 1; mask < 16; mask <<= 1) {
                float pd1 = __shfl_xor(d1, mask);
                int   pi1 = __shfl_xor(i1, mask);
                float pd2 = __shfl_xor(d2, mask);
                if (pd1 < d1 || (pd1 == d1 && pi1 < i1)) {
                    d2 = fminf(d1, pd2); d1 = pd1; i1 = pi1;
                } else d2 = fminf(d2, pd1);
            }
            if (lr == 0) {
                int row = wr * 64 + m * 16 + lk * 4 + r;   // C/D: row=(lane>>4)*4+reg
                mg_d1[row * 4 + wc] = d1;
                mg_i1[row * 4 + wc] = i1;
                mg_d2[row * 4 + wc] = d2;
            }
        }
    __syncthreads();
    if (t < 128) {
        float b1 = FLT_MAX, b2 = FLT_MAX;
        int bi = 0x7fffffff;
        #pragma unroll
        for (int c = 0; c < 4; ++c) {
            float pd1 = mg_d1[t * 4 + c];
            int   pi1 = mg_i1[t * 4 + c];
            float pd2 = mg_d2[t * 4 + c];
            if (pd1 < b1 || (pd1 == b1 && pi1 < bi)) {
                b2 = fminf(b1, pd2); b1 = pd1; bi = pi1;
            } else b2 = fminf(b2, pd1);
        }
        code[row0 + t] = bi;
        atomicAdd(&counts[bi], 1);
        if (b2 - b1 < TAUGAP) {
            int pos = atomicAdd(nflag, 1);
            flags[pos] = row0 + t;
        }
    }
}

// ---------------- batched re-resolution: 16 rows per E-pass, fp32 + fp64 candidates ----------------
__global__ __launch_bounds__(256) void k_fixup(
    const float* __restrict__ z, const float* __restrict__ E,
    const float* __restrict__ enorm, const double* __restrict__ enorm64,
    const int* __restrict__ nflag, const int* __restrict__ flags,
    int* __restrict__ code, int* __restrict__ counts) {
    __shared__ float  zrows[GROUP][256];   // 16KB
    __shared__ int    rowid[GROUP];
    __shared__ float  bw[GROUP][4];
    __shared__ float  bestAll[GROUP];
    __shared__ int    ccnt[GROUP];
    __shared__ int    cand[GROUP][16];
    __shared__ double cdist[GROUP][16];

    const int t = threadIdx.x, w = t >> 6, l = t & 63;
    const int n = *nflag;
    const int ngroups = (n + GROUP - 1) / GROUP;

    for (int g = blockIdx.x; g < ngroups; g += gridDim.x) {
        __syncthreads();
        if (t < GROUP) {
            int idx = g * GROUP + t;
            rowid[t] = (idx < n) ? flags[idx] : -1;
            ccnt[t] = 0;
        }
        __syncthreads();
        {   // stage 16 z rows
            int i = t >> 4, s = t & 15;
            int r = rowid[i];
            const float* src = z + (size_t)(r < 0 ? 0 : r) * D_ + s * 16;
            float4 a0 = *(const float4*)(src + 0);
            float4 a1 = *(const float4*)(src + 4);
            float4 a2 = *(const float4*)(src + 8);
            float4 a3 = *(const float4*)(src + 12);
            *(float4*)&zrows[i][s * 16 + 0]  = a0;
            *(float4*)&zrows[i][s * 16 + 4]  = a1;
            *(float4*)&zrows[i][s * 16 + 8]  = a2;
            *(float4*)&zrows[i][s * 16 + 12] = a3;
        }
        __syncthreads();

        float acc[GROUP][4];
        #pragma unroll
        for (int i = 0; i < GROUP; ++i) {
            acc[i][0] = 0.f; acc[i][1] = 0.f; acc[i][2] = 0.f; acc[i][3] = 0.f;
        }
        const float* Ecol = E + 4 * t;
        for (int d = 0; d < D_; ++d) {
            float4 ev = *(const float4*)(Ecol + (size_t)d * K_);
            #pragma unroll
            for (int i = 0; i < GROUP; ++i) {
                float zd = zrows[i][d];
                acc[i][0] = fmaf(zd, ev.x, acc[i][0]);
                acc[i][1] = fmaf(zd, ev.y, acc[i][1]);
                acc[i][2] = fmaf(zd, ev.z, acc[i][2]);
                acc[i][3] = fmaf(zd, ev.w, acc[i][3]);
            }
        }
        float en0 = enorm[4 * t], en1 = enorm[4 * t + 1];
        float en2 = enorm[4 * t + 2], en3 = enorm[4 * t + 3];
        #pragma unroll
        for (int i = 0; i < GROUP; ++i) {
            acc[i][0] = en0 - 2.f * acc[i][0];
            acc[i][1] = en1 - 2.f * acc[i][1];
            acc[i][2] = en2 - 2.f * acc[i][2];
            acc[i][3] = en3 - 2.f * acc[i][3];
        }
        #pragma unroll
        for (int i = 0; i < GROUP; ++i) {
            float b = fminf(fminf(acc[i][0], acc[i][1]), fminf(acc[i][2], acc[i][3]));
            #pragma unroll
            for (int m = 1; m < 64; m <<= 1) b = fminf(b, __shfl_xor(b, m));
            if (l == 0) bw[i][w] = b;
        }
        __syncthreads();
        if (t < GROUP)
            bestAll[t] = fminf(fminf(bw[t][0], bw[t][1]), fminf(bw[t][2], bw[t][3]));
        __syncthreads();
        #pragma unroll
        for (int i = 0; i < GROUP; ++i) {
            float thr = bestAll[i] + RMARGIN;
            #pragma unroll
            for (int j = 0; j < 4; ++j) {
                if (acc[i][j] <= thr) {
                    int slot = atomicAdd(&ccnt[i], 1);
                    if (slot < 16) cand[i][slot] = 4 * t + j;
                }
            }
        }
        __syncthreads();
        for (int p = w; p < GROUP * 16; p += 4) {
            int i = p >> 4, s = p & 15;
            int cn = ccnt[i];
            if (rowid[i] < 0 || cn < 2 || s >= (cn < 16 ? cn : 16)) continue;
            int c = cand[i][s];
            double dot = 0.0;
            #pragma unroll
            for (int q = 0; q < 4; ++q) {
                int d = l * 4 + q;
                dot = fma((double)zrows[i][d], (double)E[(size_t)d * K_ + c], dot);
            }
            #pragma unroll
            for (int m = 1; m < 64; m <<= 1) dot += __shfl_xor(dot, m);
            if (l == 0) cdist[i][s] = enorm64[c] - 2.0 * dot;
        }
        __syncthreads();
        if (t < GROUP) {
            int r = rowid[t];
            if (r >= 0) {
                int cn = ccnt[t]; if (cn > 16) cn = 16;
                int newc;
                if (cn <= 1) {
                    newc = cand[t][0];
                } else {
                    double bd = DBL_MAX; int bi = INT_MAX;
                    for (int s = 0; s < cn; ++s) {
                        double dv = cdist[t][s]; int ci = cand[t][s];
                        if (dv < bd || (dv == bd && ci < bi)) { bd = dv; bi = ci; }
                    }
                    newc = bi;
                }
                int oldc = code[r];
                if (newc != oldc) {
                    code[r] = newc;
                    atomicSub(&counts[oldc], 1);
                    atomicAdd(&counts[newc], 1);
                }
            }
        }
    }
}

// ---------------- scan: prefix(counts) + chunk work-list + EMA + Laplace norm ----------------
__global__ void k_scan(const int* __restrict__ counts, const float* __restrict__ cs,
                       int* __restrict__ offsets, int* __restrict__ cursor,
                       float* __restrict__ out_newcs, float* __restrict__ csnorm,
                       int* __restrict__ work, int* __restrict__ nwork) {
    __shared__ int   s[K_];
    __shared__ int   c[K_];
    __shared__ float red[K_];
    int t = threadIdx.x;
    int v = counts[t];
    int nch = (v + CHUNK - 1) / CHUNK;
    s[t] = v;
    c[t] = nch;
    float ncs = cs[t] * DECAYF + OMDECAYF * (float)v;
    out_newcs[t] = ncs;
    red[t] = ncs;
    __syncthreads();
    for (int d = 1; d < K_; d <<= 1) {
        int x = (t >= d) ? s[t - d] : 0;
        int y = (t >= d) ? c[t - d] : 0;
        __syncthreads();
        s[t] += x; c[t] += y;
        __syncthreads();
    }
    offsets[t] = s[t] - v;
    cursor[t]  = s[t] - v;
    if (t == K_ - 1) { offsets[K_] = s[t]; *nwork = c[t]; }
    int wbase = c[t] - nch;
    for (int j = 0; j < nch; ++j) work[wbase + j] = (t << 16) | j;
    for (int st = 512; st > 0; st >>= 1) {
        if (t < st) red[t] += red[t + st];
        __syncthreads();
    }
    float nsum = red[0];
    csnorm[t] = (ncs + EPSF) / (nsum + (float)K_ * EPSF) * nsum;
}

// ---------------- counting-sort: row indices into cluster order ----------------
__global__ void k_sortidx(const int* __restrict__ code, int* __restrict__ cursor,
                          int* __restrict__ sorted) {
    int r = blockIdx.x * 256 + threadIdx.x;
    int cc = code[r];
    int pos = atomicAdd(&cursor[cc], 1);
    sorted[pos] = r;
}

// ---------------- chunked segment sum (8 rows in flight) ----------------
__global__ void k_segsum(const float* __restrict__ z, const int* __restrict__ sorted,
                         const int* __restrict__ offsets, const int* __restrict__ work,
                         const int* __restrict__ nwork, float* __restrict__ emb_sum) {
    int NW = *nwork;
    int d = threadIdx.x;
    for (int i = blockIdx.x; i < NW; i += gridDim.x) {
        int wk = work[i];
        int k = wk >> 16, j = wk & 0xffff;
        int beg = offsets[k] + j * CHUNK;
        int end = min(beg + CHUNK, offsets[k + 1]);
        float s = 0.f;
        int idx = beg;
        for (; idx + 8 <= end; idx += 8) {
            int r0 = sorted[idx],     r1 = sorted[idx + 1];
            int r2 = sorted[idx + 2], r3 = sorted[idx + 3];
            int r4 = sorted[idx + 4], r5 = sorted[idx + 5];
            int r6 = sorted[idx + 6], r7 = sorted[idx + 7];
            float v0 = z[(size_t)r0 * D_ + d];
            float v1 = z[(size_t)r1 * D_ + d];
            float v2 = z[(size_t)r2 * D_ + d];
            float v3 = z[(size_t)r3 * D_ + d];
            float v4 = z[(size_t)r4 * D_ + d];
            float v5 = z[(size_t)r5 * D_ + d];
            float v6 = z[(size_t)r6 * D_ + d];
            float v7 = z[(size_t)r7 * D_ + d];
            s += ((v0 + v1) + (v2 + v3)) + ((v4 + v5) + (v6 + v7));
        }
        for (; idx < end; ++idx) s += z[(size_t)sorted[idx] * D_ + d];
        atomicAdd(&emb_sum[(size_t)k * D_ + d], s);
    }
}

// ---------------- EMA + normalized codebook ----------------
__global__ void k_emb(const float* __restrict__ EM, const float* __restrict__ emb_sum,
                      const float* __restrict__ csnorm,
                      float* __restrict__ out_newemb, float* __restrict__ out_newem,
                      float* __restrict__ newembT) {
    int tid = blockIdx.x * 256 + threadIdx.x;
    int k = tid >> 8, d = tid & 255;
    float em  = EM[(size_t)d * K_ + k];
    float nem = em * DECAYF + OMDECAYF * emb_sum[tid];
    float nq  = nem / csnorm[k];
    out_newem [(size_t)d * K_ + k] = nem;
    out_newemb[(size_t)d * K_ + k] = nq;
    newembT[tid] = nq;
}

// ---------------- gather z_q + code + loss: 8 rows/wave, ALL 8 in flight ----------------
// grid 2048 blocks x 256 threads; block owns 32 contiguous rows (never crosses b).
__global__ __launch_bounds__(256) void k_gather(
    const float* __restrict__ z, const int* __restrict__ code,
    const float* __restrict__ newembT,
    float* __restrict__ out_zq, float* __restrict__ out_code,
    float* __restrict__ out_closs) {
    __shared__ double wsum[4];
    const int w = threadIdx.x >> 6, l = threadIdx.x & 63;
    const int base = blockIdx.x * 32 + w * 8;
    // 8 wave-uniform index loads
    int i0 = code[base],     i1 = code[base + 1], i2 = code[base + 2], i3 = code[base + 3];
    int i4 = code[base + 4], i5 = code[base + 5], i6 = code[base + 6], i7 = code[base + 7];
    // 16 independent 16B loads in flight
    float4 z0 = *(const float4*)(z + (size_t)(base    ) * D_ + l * 4);
    float4 z1 = *(const float4*)(z + (size_t)(base + 1) * D_ + l * 4);
    float4 z2 = *(const float4*)(z + (size_t)(base + 2) * D_ + l * 4);
    float4 z3 = *(const float4*)(z + (size_t)(base + 3) * D_ + l * 4);
    float4 z4 = *(const float4*)(z + (size_t)(base + 4) * D_ + l * 4);
    float4 z5 = *(const float4*)(z + (size_t)(base + 5) * D_ + l * 4);
    float4 z6 = *(const float4*)(z + (size_t)(base + 6) * D_ + l * 4);
    float4 z7 = *(const float4*)(z + (size_t)(base + 7) * D_ + l * 4);
    float4 e0 = *(const float4*)(newembT + (size_t)i0 * D_ + l * 4);
    float4 e1 = *(const float4*)(newembT + (size_t)i1 * D_ + l * 4);
    float4 e2 = *(const float4*)(newembT + (size_t)i2 * D_ + l * 4);
    float4 e3 = *(const float4*)(newembT + (size_t)i3 * D_ + l * 4);
    float4 e4 = *(const float4*)(newembT + (size_t)i4 * D_ + l * 4);
    float4 e5 = *(const float4*)(newembT + (size_t)i5 * D_ + l * 4);
    float4 e6 = *(const float4*)(newembT + (size_t)i6 * D_ + l * 4);
    float4 e7 = *(const float4*)(newembT + (size_t)i7 * D_ + l * 4);
    *(float4*)(out_zq + (size_t)(base    ) * D_ + l * 4) = e0;
    *(float4*)(out_zq + (size_t)(base + 1) * D_ + l * 4) = e1;
    *(float4*)(out_zq + (size_t)(base + 2) * D_ + l * 4) = e2;
    *(float4*)(out_zq + (size_t)(base + 3) * D_ + l * 4) = e3;
    *(float4*)(out_zq + (size_t)(base + 4) * D_ + l * 4) = e4;
    *(float4*)(out_zq + (size_t)(base + 5) * D_ + l * 4) = e5;
    *(float4*)(out_zq + (size_t)(base + 6) * D_ + l * 4) = e6;
    *(float4*)(out_zq + (size_t)(base + 7) * D_ + l * 4) = e7;
    if (l == 0) {
        out_code[base]     = (float)i0; out_code[base + 1] = (float)i1;
        out_code[base + 2] = (float)i2; out_code[base + 3] = (float)i3;
        out_code[base + 4] = (float)i4; out_code[base + 5] = (float)i5;
        out_code[base + 6] = (float)i6; out_code[base + 7] = (float)i7;
    }
    double acc = 0.0;
    float dx, dy, dz2, dw2;
    dx = e0.x - z0.x; dy = e0.y - z0.y; dz2 = e0.z - z0.z; dw2 = e0.w - z0.w;
    acc += (double)dx * dx + (double)dy * dy + (double)dz2 * dz2 + (double)dw2 * dw2;
    dx = e1.x - z1.x; dy = e1.y - z1.y; dz2 = e1.z - z1.z; dw2 = e1.w - z1.w;
    acc += (double)dx * dx + (double)dy * dy + (double)dz2 * dz2 + (double)dw2 * dw2;
    dx = e2.x - z2.x; dy = e2.y - z2.y; dz2 = e2.z - z2.z; dw2 = e2.w - z2.w;
    acc += (double)dx * dx + (double)dy * dy + (double)dz2 * dz2 + (double)dw2 * dw2;
    dx = e3.x - z3.x; dy = e3.y - z3.y; dz2 = e3.z - z3.z; dw2 = e3.w - z3.w;
    acc += (double)dx * dx + (double)dy * dy + (double)dz2 * dz2 + (double)dw2 * dw2;
    dx = e4.x - z4.x; dy = e4.y - z4.y; dz2 = e4.z - z4.z; dw2 = e4.w - z4.w;
    acc += (double)dx * dx + (double)dy * dy + (double)dz2 * dz2 + (double)dw2 * dw2;
    dx = e5.x - z5.x; dy = e5.y - z5.y; dz2 = e5.z - z5.z; dw2 = e5.w - z5.w;
    acc += (double)dx * dx + (double)dy * dy + (double)dz2 * dz2 + (double)dw2 * dw2;
    dx = e6.x - z6.x; dy = e6.y - z6.y; dz2 = e6.z - z6.z; dw2 = e6.w - z6.w;
    acc += (double)dx * dx + (double)dy * dy + (double)dz2 * dz2 + (double)dw2 * dw2;
    dx = e7.x - z7.x; dy = e7.y - z7.y; dz2 = e7.z - z7.z; dw2 = e7.w - z7.w;
    acc += (double)dx * dx + (double)dy * dy + (double)dz2 * dz2 + (double)dw2 * dw2;
    #pragma unroll
    for (int off = 32; off > 0; off >>= 1) acc += __shfl_down(acc, off);
    if (l == 0) wsum[w] = acc;
    __syncthreads();
    if (threadIdx.x == 0) {
        float v = (float)((wsum[0] + wsum[1] + wsum[2] + wsum[3]) *
                          (1.0 / ((double)T_ * (double)D_)));
        atomicAdd(&out_closs[blockIdx.x >> 7], v);   // 128 blocks per batch b
    }
}

extern "C" void kernel_launch(void* const* d_in, const int* in_sizes, int n_in,
                              void* d_out, int out_size, void* d_ws, size_t ws_size,
                              hipStream_t stream) {
    (void)in_sizes; (void)n_in; (void)out_size; (void)ws_size;
    const float* z  = (const float*)d_in[0];
    const float* E  = (const float*)d_in[1];
    const float* cs = (const float*)d_in[2];
    const float* EM = (const float*)d_in[3];

    float* out       = (float*)d_out;
    float* out_zq    = out;                         // 16777216 floats
    float* out_closs = out + 16777216;              // 16
    float* out_cbl   = out_closs + 16;              // 16
    float* out_code  = out_cbl + 16;                // 65536
    float* out_nemb  = out_code + 65536;            // 262144
    float* out_ncs   = out_nemb + 262144;           // 1024
    float* out_nem   = out_ncs + 1024;              // 262144

    // fp16 z lives in the z_q output region (fully overwritten by k_gather)
    _Float16* zf = (_Float16*)out_zq;               // 32MB

    char* w = (char*)d_ws;
    int*      counts  = (int*)(w + 0);              // 4096 B (zeroed in prep)
    int*      nflag   = (int*)(w + 4096);           // 64 B   (zeroed in prep)
    int*      offsets = (int*)(w + 4160);           // 4104 B (1025 ints)
    int*      cursor  = (int*)(w + 8320);           // 4096 B
    float*    enorm   = (float*)(w + 12416);        // 4096 B
    int*      code_i  = (int*)(w + 16512);          // 262144 B
    int*      flags   = (int*)(w + 278656);         // 262144 B
    float*    csnorm  = (float*)(w + 540800);       // 4096 B
    float*    newembT = (float*)(w + 544896);       // 1048576 B
    _Float16* EfT     = (_Float16*)(w + 1593472);   // 524288 B
    int*      sorted  = (int*)(w + 2117760);        // 262144 B
    float*    emb_sum = (float*)(w + 2379904);      // 1048576 B (zeroed in prep)
    int*      work    = (int*)(w + 3428480);        // 16384 B (<=3072 items)
    int*      nwork   = (int*)(w + 3444864);        // 64 B
    double*   enorm64 = (double*)(w + 3444928);     // 8192 B  (end ~3.45 MB)

    k_prep       <<<9216, 256, 0, stream>>>(z, E, zf, EfT, enorm, enorm64, counts,
                                            nflag, out_closs, out_cbl, emb_sum);
    k_argmin_mfma<<<BT_ / 128, 512, 0, stream>>>(zf, EfT, enorm, code_i, flags,
                                                 nflag, counts);
    k_fixup      <<<256, 256, 0, stream>>>(z, E, enorm, enorm64, nflag, flags,
                                           code_i, counts);
    k_scan       <<<1, K_, 0, stream>>>(counts, cs, offsets, cursor, out_ncs, csnorm,
                                        work, nwork);
    k_sortidx    <<<BT_ / 256, 256, 0, stream>>>(code_i, cursor, sorted);
    k_segsum     <<<2048, 256, 0, stream>>>(z, sorted, offsets, work, nwork, emb_sum);
    k_emb        <<<(K_ * D_) / 256, 256, 0, stream>>>(EM, emb_sum, csnorm,
                                                       out_nemb, out_nem, newembT);
    k_gather     <<<BT_ / 32, 256, 0, stream>>>(z, code_i, newembT, out_zq, out_code,
                                                out_closs);
}

// Round 13
// 286.501 us; speedup vs baseline: 1.7123x; 1.7123x over previous
//
#include <hip/hip_runtime.h>
#include <cfloat>
#include <climits>
#include <cstdint>

#define B_ 16
#define T_ 4096
#define D_ 256
#define K_ 1024
#define BT_ 65536
#define DECAYF 0.99f
#define OMDECAYF 0.01f
#define EPSF 1e-5f
#define TAUGAP 0.125f
#define CHUNK 32
#define GROUP 16
#define RMARGIN 0.01f

typedef float f32x4 __attribute__((ext_vector_type(4)));
typedef _Float16 f16x8 __attribute__((ext_vector_type(8)));

__device__ __forceinline__ void gload16(const void* g, void* l) {
    __builtin_amdgcn_global_load_lds(
        (const __attribute__((address_space(1))) void*)g,
        (__attribute__((address_space(3))) void*)l, 16, 0, 0);
}

// ---------------- prep: z->fp16, E->fp16^T, enorm(fp32+fp64), zero accumulators ----------------
__global__ void k_prep(const float* __restrict__ z, const float* __restrict__ E,
                       _Float16* __restrict__ zf, _Float16* __restrict__ EfT,
                       float* __restrict__ enorm, double* __restrict__ enorm64,
                       int* __restrict__ counts, int* __restrict__ nflag,
                       float* __restrict__ out_closs, float* __restrict__ out_cbl,
                       float* __restrict__ emb_sum) {
    int b = blockIdx.x;
    if (b < 8192) {                       // z: 8 floats/thread -> fp16
        int base = (b * 256 + threadIdx.x) * 8;
        float4 v0 = *(const float4*)(z + base);
        float4 v1 = *(const float4*)(z + base + 4);
        f16x8 h;
        h[0] = (_Float16)v0.x; h[1] = (_Float16)v0.y;
        h[2] = (_Float16)v0.z; h[3] = (_Float16)v0.w;
        h[4] = (_Float16)v1.x; h[5] = (_Float16)v1.y;
        h[6] = (_Float16)v1.z; h[7] = (_Float16)v1.w;
        *(f16x8*)(zf + base) = h;
    } else {                              // E column n: transpose + fp16 + fp64 norm
        __shared__ double rd[256];
        int n = b - 8192, d = threadIdx.x;
        float v = E[(size_t)d * K_ + n];
        EfT[(size_t)n * 256 + d] = (_Float16)v;
        rd[d] = (double)v * (double)v;
        __syncthreads();
        for (int st = 128; st > 0; st >>= 1) {
            if (d < st) rd[d] += rd[d + st];
            __syncthreads();
        }
        if (d == 0) { enorm[n] = (float)rd[0]; enorm64[n] = rd[0]; }
        emb_sum[(size_t)n * 256 + d] = 0.f;
        if (n < 4) counts[n * 256 + d] = 0;
        if (n == 4) {
            if (d < 16) out_closs[d] = 0.f;
            else if (d < 32) out_cbl[d - 16] = 0.f;
            else if (d == 32) *nflag = 0;
        }
    }
}

// ---------------- fp16 MFMA distance GEMM + fused argmin top-2 + histogram ----------------
// R8 loop + 48KB LDS (merge aliased on Ab). launch_bounds(512,2): NO register cap
// (R12's (512,6) forced VGPR 40 -> accumulator spill, 821MB scratch writes).
// If allocator lands <=85 VGPR, HW fits 3 blocks/CU; else identical to R8.
__global__ __launch_bounds__(512, 2) void k_argmin_mfma(
    const _Float16* __restrict__ zf, const _Float16* __restrict__ EfT,
    const float* __restrict__ enorm, int* __restrict__ code,
    int* __restrict__ flags, int* __restrict__ nflag, int* __restrict__ counts) {
    __shared__ _Float16 Ab[2][128 * 32];   // 8KB x2 (epilogue aliases Ab for merge)
    __shared__ _Float16 Bb[2][256 * 32];   // 16KB x2  -> 48KB total

    const int t = threadIdx.x;
    const int row0 = blockIdx.x * 128;
    const int l = t & 63, wid = t >> 6;
    const int wr = wid >> 2, wc = wid & 3;
    const int lr = l & 15, lk = l >> 4;

    const int arow = t >> 2,          ablk = (t & 3) ^ ((arow >> 1) & 3);
    const int brow0 = t >> 2,         bblk0 = (t & 3) ^ ((brow0 >> 1) & 3);
    const int brow1 = (t + 512) >> 2, bblk1 = ((t + 512) & 3) ^ ((brow1 >> 1) & 3);

#define STAGE(it_, buf_) do {                                                       \
        int nc_ = (it_) >> 3; int kb_ = ((it_) & 7) * 32;                            \
        gload16(zf + (size_t)(row0 + arow) * 256 + kb_ + ablk * 8,                   \
                &Ab[buf_][(t & ~63) * 8]);                                           \
        gload16(EfT + (size_t)(nc_ * 256 + brow0) * 256 + kb_ + bblk0 * 8,           \
                &Bb[buf_][(t & ~63) * 8]);                                           \
        gload16(EfT + (size_t)(nc_ * 256 + brow1) * 256 + kb_ + bblk1 * 8,           \
                &Bb[buf_][((t + 512) & ~63) * 8]);                                   \
    } while (0)

    STAGE(0, 0);

    float D1[4][4], D2[4][4];
    int   I1[4][4];
    #pragma unroll
    for (int m = 0; m < 4; ++m)
        #pragma unroll
        for (int r = 0; r < 4; ++r) {
            D1[m][r] = FLT_MAX; D2[m][r] = FLT_MAX; I1[m][r] = 0x7fffffff;
        }

    f32x4 acc[4][4];
    for (int it = 0; it < 32; ++it) {
        if ((it & 7) == 0) {
            #pragma unroll
            for (int m = 0; m < 4; ++m)
                #pragma unroll
                for (int n = 0; n < 4; ++n) acc[m][n] = (f32x4){0.f, 0.f, 0.f, 0.f};
        }
        __syncthreads();                       // buf[it&1] ready
        if (it + 1 < 32) STAGE(it + 1, (it + 1) & 1);
        const _Float16* Abuf = Ab[it & 1];
        const _Float16* Bbuf = Bb[it & 1];
        f16x8 a[4], b[4];
        #pragma unroll
        for (int m = 0; m < 4; ++m) {
            int row = wr * 64 + m * 16 + lr;
            a[m] = *(const f16x8*)&Abuf[row * 32 + ((lk ^ ((row >> 1) & 3)) * 8)];
        }
        #pragma unroll
        for (int n = 0; n < 4; ++n) {
            int nn = wc * 64 + n * 16 + lr;
            b[n] = *(const f16x8*)&Bbuf[nn * 32 + ((lk ^ ((nn >> 1) & 3)) * 8)];
        }
        #pragma unroll
        for (int m = 0; m < 4; ++m)
            #pragma unroll
            for (int n = 0; n < 4; ++n)
                acc[m][n] = __builtin_amdgcn_mfma_f32_16x16x32_f16(
                    a[m], b[n], acc[m][n], 0, 0, 0);

        if ((it & 7) == 7) {                   // fold this nc chunk into running top-2
            int nc = it >> 3;
            float en[4];
            #pragma unroll
            for (int n = 0; n < 4; ++n)
                en[n] = enorm[nc * 256 + wc * 64 + n * 16 + lr];
            #pragma unroll
            for (int m = 0; m < 4; ++m)
                #pragma unroll
                for (int r = 0; r < 4; ++r)
                    #pragma unroll
                    for (int n = 0; n < 4; ++n) {
                        float dist = en[n] - 2.0f * acc[m][n][r];
                        int cg = nc * 256 + wc * 64 + n * 16 + lr;
                        if (dist < D1[m][r]) {
                            D2[m][r] = D1[m][r]; D1[m][r] = dist; I1[m][r] = cg;
                        } else D2[m][r] = fminf(D2[m][r], dist);
                    }
        }
    }
#undef STAGE

    // ---- final merge: 16 lr-lanes -> mg (aliased on Ab) -> 4 wc ----
    __syncthreads();   // all Ab/Bb reads complete; safe to reuse Ab as merge scratch
    float* mg_d1 = (float*)&Ab[0][0];
    int*   mg_i1 = (int*)(mg_d1 + 512);
    float* mg_d2 = (float*)(mg_i1 + 512);

    #pragma unroll
    for (int m = 0; m < 4; ++m)
        #pragma unroll
        for (int r = 0; r < 4; ++r) {
            float d1 = D1[m][r], d2 = D2[m][r];
            int i1 = I1[m][r];
            #pragma unroll
            for (int mask = 1; mask < 16; mask <<= 1) {
                float pd1 = __shfl_xor(d1, mask);
                int   pi1 = __shfl_xor(i1, mask);
                float pd2 = __shfl_xor(d2, mask);
                if (pd1 < d1 || (pd1 == d1 && pi1 < i1)) {
                    d2 = fminf(d1, pd2); d1 = pd1; i1 = pi1;
                } else d2 = fminf(d2, pd1);
            }
            if (lr == 0) {
                int row = wr * 64 + m * 16 + lk * 4 + r;   // C/D: row=(lane>>4)*4+reg
                mg_d1[row * 4 + wc] = d1;
                mg_i1[row * 4 + wc] = i1;
                mg_d2[row * 4 + wc] = d2;
            }
        }
    __syncthreads();
    if (t < 128) {
        float b1 = FLT_MAX, b2 = FLT_MAX;
        int bi = 0x7fffffff;
        #pragma unroll
        for (int c = 0; c < 4; ++c) {
            float pd1 = mg_d1[t * 4 + c];
            int   pi1 = mg_i1[t * 4 + c];
            float pd2 = mg_d2[t * 4 + c];
            if (pd1 < b1 || (pd1 == b1 && pi1 < bi)) {
                b2 = fminf(b1, pd2); b1 = pd1; bi = pi1;
            } else b2 = fminf(b2, pd1);
        }
        code[row0 + t] = bi;
        atomicAdd(&counts[bi], 1);
        if (b2 - b1 < TAUGAP) {
            int pos = atomicAdd(nflag, 1);
            flags[pos] = row0 + t;
        }
    }
}

// ---------------- batched re-resolution: 16 rows per E-pass, fp32 + fp64 candidates ----------------
__global__ __launch_bounds__(256) void k_fixup(
    const float* __restrict__ z, const float* __restrict__ E,
    const float* __restrict__ enorm, const double* __restrict__ enorm64,
    const int* __restrict__ nflag, const int* __restrict__ flags,
    int* __restrict__ code, int* __restrict__ counts) {
    __shared__ float  zrows[GROUP][256];   // 16KB
    __shared__ int    rowid[GROUP];
    __shared__ float  bw[GROUP][4];
    __shared__ float  bestAll[GROUP];
    __shared__ int    ccnt[GROUP];
    __shared__ int    cand[GROUP][16];
    __shared__ double cdist[GROUP][16];

    const int t = threadIdx.x, w = t >> 6, l = t & 63;
    const int n = *nflag;
    const int ngroups = (n + GROUP - 1) / GROUP;

    for (int g = blockIdx.x; g < ngroups; g += gridDim.x) {
        __syncthreads();
        if (t < GROUP) {
            int idx = g * GROUP + t;
            rowid[t] = (idx < n) ? flags[idx] : -1;
            ccnt[t] = 0;
        }
        __syncthreads();
        {   // stage 16 z rows
            int i = t >> 4, s = t & 15;
            int r = rowid[i];
            const float* src = z + (size_t)(r < 0 ? 0 : r) * D_ + s * 16;
            float4 a0 = *(const float4*)(src + 0);
            float4 a1 = *(const float4*)(src + 4);
            float4 a2 = *(const float4*)(src + 8);
            float4 a3 = *(const float4*)(src + 12);
            *(float4*)&zrows[i][s * 16 + 0]  = a0;
            *(float4*)&zrows[i][s * 16 + 4]  = a1;
            *(float4*)&zrows[i][s * 16 + 8]  = a2;
            *(float4*)&zrows[i][s * 16 + 12] = a3;
        }
        __syncthreads();

        float acc[GROUP][4];
        #pragma unroll
        for (int i = 0; i < GROUP; ++i) {
            acc[i][0] = 0.f; acc[i][1] = 0.f; acc[i][2] = 0.f; acc[i][3] = 0.f;
        }
        const float* Ecol = E + 4 * t;
        for (int d = 0; d < D_; ++d) {
            float4 ev = *(const float4*)(Ecol + (size_t)d * K_);
            #pragma unroll
            for (int i = 0; i < GROUP; ++i) {
                float zd = zrows[i][d];
                acc[i][0] = fmaf(zd, ev.x, acc[i][0]);
                acc[i][1] = fmaf(zd, ev.y, acc[i][1]);
                acc[i][2] = fmaf(zd, ev.z, acc[i][2]);
                acc[i][3] = fmaf(zd, ev.w, acc[i][3]);
            }
        }
        float en0 = enorm[4 * t], en1 = enorm[4 * t + 1];
        float en2 = enorm[4 * t + 2], en3 = enorm[4 * t + 3];
        #pragma unroll
        for (int i = 0; i < GROUP; ++i) {
            acc[i][0] = en0 - 2.f * acc[i][0];
            acc[i][1] = en1 - 2.f * acc[i][1];
            acc[i][2] = en2 - 2.f * acc[i][2];
            acc[i][3] = en3 - 2.f * acc[i][3];
        }
        #pragma unroll
        for (int i = 0; i < GROUP; ++i) {
            float b = fminf(fminf(acc[i][0], acc[i][1]), fminf(acc[i][2], acc[i][3]));
            #pragma unroll
            for (int m = 1; m < 64; m <<= 1) b = fminf(b, __shfl_xor(b, m));
            if (l == 0) bw[i][w] = b;
        }
        __syncthreads();
        if (t < GROUP)
            bestAll[t] = fminf(fminf(bw[t][0], bw[t][1]), fminf(bw[t][2], bw[t][3]));
        __syncthreads();
        #pragma unroll
        for (int i = 0; i < GROUP; ++i) {
            float thr = bestAll[i] + RMARGIN;
            #pragma unroll
            for (int j = 0; j < 4; ++j) {
                if (acc[i][j] <= thr) {
                    int slot = atomicAdd(&ccnt[i], 1);
                    if (slot < 16) cand[i][slot] = 4 * t + j;
                }
            }
        }
        __syncthreads();
        for (int p = w; p < GROUP * 16; p += 4) {
            int i = p >> 4, s = p & 15;
            int cn = ccnt[i];
            if (rowid[i] < 0 || cn < 2 || s >= (cn < 16 ? cn : 16)) continue;
            int c = cand[i][s];
            double dot = 0.0;
            #pragma unroll
            for (int q = 0; q < 4; ++q) {
                int d = l * 4 + q;
                dot = fma((double)zrows[i][d], (double)E[(size_t)d * K_ + c], dot);
            }
            #pragma unroll
            for (int m = 1; m < 64; m <<= 1) dot += __shfl_xor(dot, m);
            if (l == 0) cdist[i][s] = enorm64[c] - 2.0 * dot;
        }
        __syncthreads();
        if (t < GROUP) {
            int r = rowid[t];
            if (r >= 0) {
                int cn = ccnt[t]; if (cn > 16) cn = 16;
                int newc;
                if (cn <= 1) {
                    newc = cand[t][0];
                } else {
                    double bd = DBL_MAX; int bi = INT_MAX;
                    for (int s = 0; s < cn; ++s) {
                        double dv = cdist[t][s]; int ci = cand[t][s];
                        if (dv < bd || (dv == bd && ci < bi)) { bd = dv; bi = ci; }
                    }
                    newc = bi;
                }
                int oldc = code[r];
                if (newc != oldc) {
                    code[r] = newc;
                    atomicSub(&counts[oldc], 1);
                    atomicAdd(&counts[newc], 1);
                }
            }
        }
    }
}

// ---------------- scan: prefix(counts) + chunk work-list + EMA + Laplace norm ----------------
__global__ void k_scan(const int* __restrict__ counts, const float* __restrict__ cs,
                       int* __restrict__ offsets, int* __restrict__ cursor,
                       float* __restrict__ out_newcs, float* __restrict__ csnorm,
                       int* __restrict__ work, int* __restrict__ nwork) {
    __shared__ int   s[K_];
    __shared__ int   c[K_];
    __shared__ float red[K_];
    int t = threadIdx.x;
    int v = counts[t];
    int nch = (v + CHUNK - 1) / CHUNK;
    s[t] = v;
    c[t] = nch;
    float ncs = cs[t] * DECAYF + OMDECAYF * (float)v;
    out_newcs[t] = ncs;
    red[t] = ncs;
    __syncthreads();
    for (int d = 1; d < K_; d <<= 1) {
        int x = (t >= d) ? s[t - d] : 0;
        int y = (t >= d) ? c[t - d] : 0;
        __syncthreads();
        s[t] += x; c[t] += y;
        __syncthreads();
    }
    offsets[t] = s[t] - v;
    cursor[t]  = s[t] - v;
    if (t == K_ - 1) { offsets[K_] = s[t]; *nwork = c[t]; }
    int wbase = c[t] - nch;
    for (int j = 0; j < nch; ++j) work[wbase + j] = (t << 16) | j;
    for (int st = 512; st > 0; st >>= 1) {
        if (t < st) red[t] += red[t + st];
        __syncthreads();
    }
    float nsum = red[0];
    csnorm[t] = (ncs + EPSF) / (nsum + (float)K_ * EPSF) * nsum;
}

// ---------------- counting-sort: row indices into cluster order ----------------
__global__ void k_sortidx(const int* __restrict__ code, int* __restrict__ cursor,
                          int* __restrict__ sorted) {
    int r = blockIdx.x * 256 + threadIdx.x;
    int cc = code[r];
    int pos = atomicAdd(&cursor[cc], 1);
    sorted[pos] = r;
}

// ---------------- chunked segment sum (8 rows in flight) ----------------
__global__ void k_segsum(const float* __restrict__ z, const int* __restrict__ sorted,
                         const int* __restrict__ offsets, const int* __restrict__ work,
                         const int* __restrict__ nwork, float* __restrict__ emb_sum) {
    int NW = *nwork;
    int d = threadIdx.x;
    for (int i = blockIdx.x; i < NW; i += gridDim.x) {
        int wk = work[i];
        int k = wk >> 16, j = wk & 0xffff;
        int beg = offsets[k] + j * CHUNK;
        int end = min(beg + CHUNK, offsets[k + 1]);
        float s = 0.f;
        int idx = beg;
        for (; idx + 8 <= end; idx += 8) {
            int r0 = sorted[idx],     r1 = sorted[idx + 1];
            int r2 = sorted[idx + 2], r3 = sorted[idx + 3];
            int r4 = sorted[idx + 4], r5 = sorted[idx + 5];
            int r6 = sorted[idx + 6], r7 = sorted[idx + 7];
            float v0 = z[(size_t)r0 * D_ + d];
            float v1 = z[(size_t)r1 * D_ + d];
            float v2 = z[(size_t)r2 * D_ + d];
            float v3 = z[(size_t)r3 * D_ + d];
            float v4 = z[(size_t)r4 * D_ + d];
            float v5 = z[(size_t)r5 * D_ + d];
            float v6 = z[(size_t)r6 * D_ + d];
            float v7 = z[(size_t)r7 * D_ + d];
            s += ((v0 + v1) + (v2 + v3)) + ((v4 + v5) + (v6 + v7));
        }
        for (; idx < end; ++idx) s += z[(size_t)sorted[idx] * D_ + d];
        atomicAdd(&emb_sum[(size_t)k * D_ + d], s);
    }
}

// ---------------- EMA + normalized codebook ----------------
__global__ void k_emb(const float* __restrict__ EM, const float* __restrict__ emb_sum,
                      const float* __restrict__ csnorm,
                      float* __restrict__ out_newemb, float* __restrict__ out_newem,
                      float* __restrict__ newembT) {
    int tid = blockIdx.x * 256 + threadIdx.x;
    int k = tid >> 8, d = tid & 255;
    float em  = EM[(size_t)d * K_ + k];
    float nem = em * DECAYF + OMDECAYF * emb_sum[tid];
    float nq  = nem / csnorm[k];
    out_newem [(size_t)d * K_ + k] = nem;
    out_newemb[(size_t)d * K_ + k] = nq;
    newembT[tid] = nq;
}

// ---------------- gather z_q + code + loss: 8 rows/wave, ALL 8 in flight ----------------
__global__ __launch_bounds__(256) void k_gather(
    const float* __restrict__ z, const int* __restrict__ code,
    const float* __restrict__ newembT,
    float* __restrict__ out_zq, float* __restrict__ out_code,
    float* __restrict__ out_closs) {
    __shared__ double wsum[4];
    const int w = threadIdx.x >> 6, l = threadIdx.x & 63;
    const int base = blockIdx.x * 32 + w * 8;
    int i0 = code[base],     i1 = code[base + 1], i2 = code[base + 2], i3 = code[base + 3];
    int i4 = code[base + 4], i5 = code[base + 5], i6 = code[base + 6], i7 = code[base + 7];
    float4 z0 = *(const float4*)(z + (size_t)(base    ) * D_ + l * 4);
    float4 z1 = *(const float4*)(z + (size_t)(base + 1) * D_ + l * 4);
    float4 z2 = *(const float4*)(z + (size_t)(base + 2) * D_ + l * 4);
    float4 z3 = *(const float4*)(z + (size_t)(base + 3) * D_ + l * 4);
    float4 z4 = *(const float4*)(z + (size_t)(base + 4) * D_ + l * 4);
    float4 z5 = *(const float4*)(z + (size_t)(base + 5) * D_ + l * 4);
    float4 z6 = *(const float4*)(z + (size_t)(base + 6) * D_ + l * 4);
    float4 z7 = *(const float4*)(z + (size_t)(base + 7) * D_ + l * 4);
    float4 e0 = *(const float4*)(newembT + (size_t)i0 * D_ + l * 4);
    float4 e1 = *(const float4*)(newembT + (size_t)i1 * D_ + l * 4);
    float4 e2 = *(const float4*)(newembT + (size_t)i2 * D_ + l * 4);
    float4 e3 = *(const float4*)(newembT + (size_t)i3 * D_ + l * 4);
    float4 e4 = *(const float4*)(newembT + (size_t)i4 * D_ + l * 4);
    float4 e5 = *(const float4*)(newembT + (size_t)i5 * D_ + l * 4);
    float4 e6 = *(const float4*)(newembT + (size_t)i6 * D_ + l * 4);
    float4 e7 = *(const float4*)(newembT + (size_t)i7 * D_ + l * 4);
    *(float4*)(out_zq + (size_t)(base    ) * D_ + l * 4) = e0;
    *(float4*)(out_zq + (size_t)(base + 1) * D_ + l * 4) = e1;
    *(float4*)(out_zq + (size_t)(base + 2) * D_ + l * 4) = e2;
    *(float4*)(out_zq + (size_t)(base + 3) * D_ + l * 4) = e3;
    *(float4*)(out_zq + (size_t)(base + 4) * D_ + l * 4) = e4;
    *(float4*)(out_zq + (size_t)(base + 5) * D_ + l * 4) = e5;
    *(float4*)(out_zq + (size_t)(base + 6) * D_ + l * 4) = e6;
    *(float4*)(out_zq + (size_t)(base + 7) * D_ + l * 4) = e7;
    if (l == 0) {
        out_code[base]     = (float)i0; out_code[base + 1] = (float)i1;
        out_code[base + 2] = (float)i2; out_code[base + 3] = (float)i3;
        out_code[base + 4] = (float)i4; out_code[base + 5] = (float)i5;
        out_code[base + 6] = (float)i6; out_code[base + 7] = (float)i7;
    }
    double acc = 0.0;
    float dx, dy, dz2, dw2;
    dx = e0.x - z0.x; dy = e0.y - z0.y; dz2 = e0.z - z0.z; dw2 = e0.w - z0.w;
    acc += (double)dx * dx + (double)dy * dy + (double)dz2 * dz2 + (double)dw2 * dw2;
    dx = e1.x - z1.x; dy = e1.y - z1.y; dz2 = e1.z - z1.z; dw2 = e1.w - z1.w;
    acc += (double)dx * dx + (double)dy * dy + (double)dz2 * dz2 + (double)dw2 * dw2;
    dx = e2.x - z2.x; dy = e2.y - z2.y; dz2 = e2.z - z2.z; dw2 = e2.w - z2.w;
    acc += (double)dx * dx + (double)dy * dy + (double)dz2 * dz2 + (double)dw2 * dw2;
    dx = e3.x - z3.x; dy = e3.y - z3.y; dz2 = e3.z - z3.z; dw2 = e3.w - z3.w;
    acc += (double)dx * dx + (double)dy * dy + (double)dz2 * dz2 + (double)dw2 * dw2;
    dx = e4.x - z4.x; dy = e4.y - z4.y; dz2 = e4.z - z4.z; dw2 = e4.w - z4.w;
    acc += (double)dx * dx + (double)dy * dy + (double)dz2 * dz2 + (double)dw2 * dw2;
    dx = e5.x - z5.x; dy = e5.y - z5.y; dz2 = e5.z - z5.z; dw2 = e5.w - z5.w;
    acc += (double)dx * dx + (double)dy * dy + (double)dz2 * dz2 + (double)dw2 * dw2;
    dx = e6.x - z6.x; dy = e6.y - z6.y; dz2 = e6.z - z6.z; dw2 = e6.w - z6.w;
    acc += (double)dx * dx + (double)dy * dy + (double)dz2 * dz2 + (double)dw2 * dw2;
    dx = e7.x - z7.x; dy = e7.y - z7.y; dz2 = e7.z - z7.z; dw2 = e7.w - z7.w;
    acc += (double)dx * dx + (double)dy * dy + (double)dz2 * dz2 + (double)dw2 * dw2;
    #pragma unroll
    for (int off = 32; off > 0; off >>= 1) acc += __shfl_down(acc, off);
    if (l == 0) wsum[w] = acc;
    __syncthreads();
    if (threadIdx.x == 0) {
        float v = (float)((wsum[0] + wsum[1] + wsum[2] + wsum[3]) *
                          (1.0 / ((double)T_ * (double)D_)));
        atomicAdd(&out_closs[blockIdx.x >> 7], v);   // 128 blocks per batch b
    }
}

extern "C" void kernel_launch(void* const* d_in, const int* in_sizes, int n_in,
                              void* d_out, int out_size, void* d_ws, size_t ws_size,
                              hipStream_t stream) {
    (void)in_sizes; (void)n_in; (void)out_size; (void)ws_size;
    const float* z  = (const float*)d_in[0];
    const float* E  = (const float*)d_in[1];
    const float* cs = (const float*)d_in[2];
    const float* EM = (const float*)d_in[3];

    float* out       = (float*)d_out;
    float* out_zq    = out;                         // 16777216 floats
    float* out_closs = out + 16777216;              // 16
    float* out_cbl   = out_closs + 16;              // 16
    float* out_code  = out_cbl + 16;                // 65536
    float* out_nemb  = out_code + 65536;            // 262144
    float* out_ncs   = out_nemb + 262144;           // 1024
    float* out_nem   = out_ncs + 1024;              // 262144

    // fp16 z lives in the z_q output region (fully overwritten by k_gather)
    _Float16* zf = (_Float16*)out_zq;               // 32MB

    char* w = (char*)d_ws;
    int*      counts  = (int*)(w + 0);              // 4096 B (zeroed in prep)
    int*      nflag   = (int*)(w + 4096);           // 64 B   (zeroed in prep)
    int*      offsets = (int*)(w + 4160);           // 4104 B (1025 ints)
    int*      cursor  = (int*)(w + 8320);           // 4096 B
    float*    enorm   = (float*)(w + 12416);        // 4096 B
    int*      code_i  = (int*)(w + 16512);          // 262144 B
    int*      flags   = (int*)(w + 278656);         // 262144 B
    float*    csnorm  = (float*)(w + 540800);       // 4096 B
    float*    newembT = (float*)(w + 544896);       // 1048576 B
    _Float16* EfT     = (_Float16*)(w + 1593472);   // 524288 B
    int*      sorted  = (int*)(w + 2117760);        // 262144 B
    float*    emb_sum = (float*)(w + 2379904);      // 1048576 B (zeroed in prep)
    int*      work    = (int*)(w + 3428480);        // 16384 B (<=3072 items)
    int*      nwork   = (int*)(w + 3444864);        // 64 B
    double*   enorm64 = (double*)(w + 3444928);     // 8192 B  (end ~3.45 MB)

    k_prep       <<<9216, 256, 0, stream>>>(z, E, zf, EfT, enorm, enorm64, counts,
                                            nflag, out_closs, out_cbl, emb_sum);
    k_argmin_mfma<<<BT_ / 128, 512, 0, stream>>>(zf, EfT, enorm, code_i, flags,
                                                 nflag, counts);
    k_fixup      <<<256, 256, 0, stream>>>(z, E, enorm, enorm64, nflag, flags,
                                           code_i, counts);
    k_scan       <<<1, K_, 0, stream>>>(counts, cs, offsets, cursor, out_ncs, csnorm,
                                        work, nwork);
    k_sortidx    <<<BT_ / 256, 256, 0, stream>>>(code_i, cursor, sorted);
    k_segsum     <<<2048, 256, 0, stream>>>(z, sorted, offsets, work, nwork, emb_sum);
    k_emb        <<<(K_ * D_) / 256, 256, 0, stream>>>(EM, emb_sum, csnorm,
                                                       out_nemb, out_nem, newembT);
    k_gather     <<<BT_ / 32, 256, 0, stream>>>(z, code_i, newembT, out_zq, out_code,
                                                out_closs);
}